// Round 3
// baseline (25444.739 us; speedup 1.0000x reference)
//
#include <hip/hip_runtime.h>
#include <hip/hip_bf16.h>
#include <hip/hip_cooperative_groups.h>

// LSTM: N=32, T=1024, D=H=512. Persistent cooperative kernel, 32 WGs.
// WG w owns gate-columns j in [16w,16w+16) of all 4 gates; wave g = gate g.
// Weights' column slices live (bf16) transposed in LDS for the whole run.
// Per step: [x_t | h_{t-1}] @ [Wx;Wh] via mfma_f32_16x16x32_bf16, gate
// exchange via LDS, fp32 c in LDS. h_t written to out[:,t,:]; step t+1 reads
// h from out[:,t,:] (per-step history -> no overwrite race; one grid.sync/step).
//
// DTYPE-PROOF: device-side sniff of Wx halfwords decides fp32 vs bf16 dataset
// (uniform branch). fp32 body: weights/x rounded to bf16, h kept fp32 via
// on-the-fly hi+lo split (2 MFMA terms) -> recurrent path fp32-grade; out fp32.
// bf16 body: round-2 logic; out bf16. ws unused.

#define NWG 32
#define LDW 520              // 512 + 8 pad shorts
#define SMEM_BYTES (2*64*LDW*2 + 4*32*16*4 + 512*4)   // 143360 B

typedef __attribute__((ext_vector_type(8))) short s16x8;
typedef __attribute__((ext_vector_type(4))) float f32x4;
typedef __attribute__((ext_vector_type(4))) float f4v;

__device__ __forceinline__ float b2f(unsigned short u) {
  unsigned v = ((unsigned)u) << 16;
  return __builtin_bit_cast(float, v);
}
__device__ __forceinline__ unsigned short f2b(float f) {
  unsigned u = __builtin_bit_cast(unsigned, f);
  unsigned r = (u + 0x7fffu + ((u >> 16) & 1u)) >> 16;  // RNE
  return (unsigned short)r;
}
__device__ __forceinline__ float sigmoidf_(float x) {
  return 1.f / (1.f + __expf(-x));
}
__device__ __forceinline__ float tanhf_(float x) {
  float ax = fabsf(x);
  float e = __expf(-2.f * ax);          // in (0,1], no overflow
  float th = (1.f - e) / (1.f + e);
  return copysignf(th, x);
}

// fp32[8] -> bf16 hi + bf16 lo fragments (hi+lo reproduces f to ~2^-17 rel)
__device__ __forceinline__ void split8(const float* p, s16x8& hi, s16x8& lo) {
  float tmp[8];
  *(f4v*)&tmp[0] = *(const f4v*)&p[0];
  *(f4v*)&tmp[4] = *(const f4v*)&p[4];
#pragma unroll
  for (int j = 0; j < 8; j++) {
    unsigned short h = f2b(tmp[j]);
    hi[j] = (short)h;
    lo[j] = (short)f2b(tmp[j] - b2f(h));
  }
}
__device__ __forceinline__ s16x8 cvt8(const float* p) {
  float tmp[8];
  *(f4v*)&tmp[0] = *(const f4v*)&p[0];
  *(f4v*)&tmp[4] = *(const f4v*)&p[4];
  s16x8 r;
#pragma unroll
  for (int j = 0; j < 8; j++) r[j] = (short)f2b(tmp[j]);
  return r;
}

// Uniform dtype sniff: bf16 normals have exponent-field in a narrow band;
// fp32-as-halfwords has uniform low halves. ~511/512 vs ~320/512 hits.
__device__ __forceinline__ bool sniff_is_bf16(const unsigned short* wx) {
  int cnt = 0;
  for (int i = 0; i < 512; i++) {
    unsigned e = (wx[i] >> 7) & 0xFF;
    cnt += (e >= 0x60 && e <= 0x9F) ? 1 : 0;
  }
  return cnt >= 440;
}

template <bool F32>
__device__ __forceinline__ void lstm_body(
    const void* xv, const void* h0v, const void* Wxv, const void* Whv,
    const void* biasv, void* outv, unsigned char* smem) {
  unsigned short* WhS = (unsigned short*)smem;                    // [64][LDW] bf16
  unsigned short* WxS = (unsigned short*)(smem + 64 * LDW * 2);   // [64][LDW] bf16
  float* gatebuf = (float*)(smem + 2 * 64 * LDW * 2);             // [4*32][16]
  float* cbuf = (float*)(smem + 2 * 64 * LDW * 2 + 4 * 32 * 16 * 4); // [512]

  const unsigned short* xb = (const unsigned short*)xv;
  const float* xf = (const float*)xv;
  const unsigned short* h0b = (const unsigned short*)h0v;
  const float* h0f = (const float*)h0v;

  const int tid = threadIdx.x;
  const int g = tid >> 6;          // wave = gate (i,f,o,g)
  const int lane = tid & 63;
  const int lm = lane & 15;
  const int q = lane >> 4;
  const int w = blockIdx.x;        // owns cols w*16 .. w*16+15 of each gate

  // One-time staging of weight column slices -> LDS [col][k], bf16.
  for (int i = 0; i < 8; i++) {
    int id = tid + i * 256;        // 0..2047
    int gate = id & 3;
    int k = id >> 2;               // 0..511
    size_t base = (size_t)k * 2048 + gate * 512 + w * 16;
    if (F32) {
      const float* px = (const float*)Wxv + base;
      const float* ph = (const float*)Whv + base;
#pragma unroll
      for (int seg = 0; seg < 4; seg++) {
        f4v vx = *(const f4v*)(px + seg * 4);
        f4v vh = *(const f4v*)(ph + seg * 4);
#pragma unroll
        for (int j = 0; j < 4; j++) {
          WxS[(gate * 16 + seg * 4 + j) * LDW + k] = f2b(vx[j]);
          WhS[(gate * 16 + seg * 4 + j) * LDW + k] = f2b(vh[j]);
        }
      }
    } else {
      const unsigned short* px = (const unsigned short*)Wxv + base;
      const unsigned short* ph = (const unsigned short*)Whv + base;
      s16x8 vx0 = *(const s16x8*)&px[0];
      s16x8 vx1 = *(const s16x8*)&px[8];
      s16x8 vh0 = *(const s16x8*)&ph[0];
      s16x8 vh1 = *(const s16x8*)&ph[8];
#pragma unroll
      for (int j = 0; j < 8; j++) {
        WxS[(gate * 16 + j) * LDW + k]     = (unsigned short)vx0[j];
        WxS[(gate * 16 + 8 + j) * LDW + k] = (unsigned short)vx1[j];
        WhS[(gate * 16 + j) * LDW + k]     = (unsigned short)vh0[j];
        WhS[(gate * 16 + 8 + j) * LDW + k] = (unsigned short)vh1[j];
      }
    }
  }
  cbuf[tid] = 0.f;
  cbuf[tid + 256] = 0.f;

  float bv[2][4];
  for (int pp = 0; pp < 2; pp++) {
    int p = tid + pp * 256;
    int j = p & 15;
    for (int qq = 0; qq < 4; qq++) {
      int idx = qq * 512 + w * 16 + j;
      bv[pp][qq] = F32 ? ((const float*)biasv)[idx]
                       : b2f(((const unsigned short*)biasv)[idx]);
    }
  }
  __syncthreads();

  cooperative_groups::grid_group grid = cooperative_groups::this_grid();

  for (int t = 0; t < 1024; t++) {
    f32x4 acc0 = {0.f, 0.f, 0.f, 0.f};   // batch rows 0..15
    f32x4 acc1 = {0.f, 0.f, 0.f, 0.f};   // batch rows 16..31

    if (F32) {
      float* outf = (float*)outv;
      const float* hpf = (t == 0) ? h0f : outf + (size_t)(t - 1) * 512;
      const size_t hstride = (t == 0) ? 512 : (size_t)1024 * 512;
      for (int kc = 0; kc < 16; kc++) {
        int k = kc * 32 + q * 8;
        s16x8 bfrag = *(const s16x8*)&WhS[(g * 16 + lm) * LDW + k];
        s16x8 hi0, lo0, hi1, lo1;
        split8(&hpf[lm * hstride + k], hi0, lo0);
        split8(&hpf[(16 + lm) * hstride + k], hi1, lo1);
        acc0 = __builtin_amdgcn_mfma_f32_16x16x32_bf16(hi0, bfrag, acc0, 0, 0, 0);
        acc0 = __builtin_amdgcn_mfma_f32_16x16x32_bf16(lo0, bfrag, acc0, 0, 0, 0);
        acc1 = __builtin_amdgcn_mfma_f32_16x16x32_bf16(hi1, bfrag, acc1, 0, 0, 0);
        acc1 = __builtin_amdgcn_mfma_f32_16x16x32_bf16(lo1, bfrag, acc1, 0, 0, 0);
      }
      for (int kc = 0; kc < 16; kc++) {
        int k = kc * 32 + q * 8;
        s16x8 bfrag = *(const s16x8*)&WxS[(g * 16 + lm) * LDW + k];
        s16x8 a0 = cvt8(&xf[(size_t)(lm * 1024 + t) * 512 + k]);
        s16x8 a1 = cvt8(&xf[(size_t)((16 + lm) * 1024 + t) * 512 + k]);
        acc0 = __builtin_amdgcn_mfma_f32_16x16x32_bf16(a0, bfrag, acc0, 0, 0, 0);
        acc1 = __builtin_amdgcn_mfma_f32_16x16x32_bf16(a1, bfrag, acc1, 0, 0, 0);
      }
    } else {
      unsigned short* outb = (unsigned short*)outv;
      const unsigned short* hpb = (t == 0) ? h0b : outb + (size_t)(t - 1) * 512;
      const size_t hstride = (t == 0) ? 512 : (size_t)1024 * 512;
      for (int kc = 0; kc < 16; kc++) {
        int k = kc * 32 + q * 8;
        s16x8 bfrag = *(const s16x8*)&WhS[(g * 16 + lm) * LDW + k];
        s16x8 a0 = *(const s16x8*)&hpb[lm * hstride + k];
        s16x8 a1 = *(const s16x8*)&hpb[(16 + lm) * hstride + k];
        acc0 = __builtin_amdgcn_mfma_f32_16x16x32_bf16(a0, bfrag, acc0, 0, 0, 0);
        acc1 = __builtin_amdgcn_mfma_f32_16x16x32_bf16(a1, bfrag, acc1, 0, 0, 0);
      }
      for (int kc = 0; kc < 16; kc++) {
        int k = kc * 32 + q * 8;
        s16x8 bfrag = *(const s16x8*)&WxS[(g * 16 + lm) * LDW + k];
        s16x8 a0 = *(const s16x8*)&xb[(size_t)(lm * 1024 + t) * 512 + k];
        s16x8 a1 = *(const s16x8*)&xb[(size_t)((16 + lm) * 1024 + t) * 512 + k];
        acc0 = __builtin_amdgcn_mfma_f32_16x16x32_bf16(a0, bfrag, acc0, 0, 0, 0);
        acc1 = __builtin_amdgcn_mfma_f32_16x16x32_bf16(a1, bfrag, acc1, 0, 0, 0);
      }
    }

    // C/D layout: col = lane&15 (j), row = q*4 + reg (batch row in 16-block)
    for (int r = 0; r < 4; r++) {
      gatebuf[(g * 32 + q * 4 + r) * 16 + lm] = acc0[r];
      gatebuf[(g * 32 + 16 + q * 4 + r) * 16 + lm] = acc1[r];
    }
    __syncthreads();

    for (int pp = 0; pp < 2; pp++) {
      int p = tid + pp * 256;
      int n = p >> 4, j = p & 15;
      float ai = gatebuf[(0 * 32 + n) * 16 + j] + bv[pp][0];
      float af = gatebuf[(1 * 32 + n) * 16 + j] + bv[pp][1];
      float ao = gatebuf[(2 * 32 + n) * 16 + j] + bv[pp][2];
      float ag = gatebuf[(3 * 32 + n) * 16 + j] + bv[pp][3];
      float iG = sigmoidf_(ai);
      float fG = sigmoidf_(af);
      float oG = sigmoidf_(ao);
      float gG = tanhf_(ag);
      float c = fG * cbuf[p] + iG * gG;
      cbuf[p] = c;
      float h = oG * tanhf_(c);
      size_t oidx = (size_t)(n * 1024 + t) * 512 + w * 16 + j;
      if (F32) ((float*)outv)[oidx] = h;
      else     ((unsigned short*)outv)[oidx] = f2b(h);
    }
    if (t == 1023) break;
    grid.sync();   // publish out[:,t,:]; also separates gatebuf/cbuf epochs
  }
}

__global__ __launch_bounds__(256) void lstm_kernel(
    const void* x, const void* h0, const void* Wx, const void* Wh,
    const void* bias, void* out) {
  extern __shared__ unsigned char smem[];
  // Uniform (data-determined) branch: same for every thread and every call.
  if (sniff_is_bf16((const unsigned short*)Wx))
    lstm_body<false>(x, h0, Wx, Wh, bias, out, smem);
  else
    lstm_body<true>(x, h0, Wx, Wh, bias, out, smem);
}

extern "C" void kernel_launch(void* const* d_in, const int* in_sizes, int n_in,
                              void* d_out, int out_size, void* d_ws, size_t ws_size,
                              hipStream_t stream) {
  const void* x  = d_in[0];
  const void* h0 = d_in[1];
  const void* Wx = d_in[2];
  const void* Wh = d_in[3];
  const void* b  = d_in[4];
  void* out = d_out;

  hipFuncSetAttribute((const void*)lstm_kernel,
                      hipFuncAttributeMaxDynamicSharedMemorySize, SMEM_BYTES);

  void* args[] = {(void*)&x, (void*)&h0, (void*)&Wx, (void*)&Wh,
                  (void*)&b, (void*)&out};
  hipLaunchCooperativeKernel((const void*)lstm_kernel, dim3(NWG), dim3(256),
                             args, SMEM_BYTES, stream);
}

// Round 4
// 21560.220 us; speedup vs baseline: 1.1802x; 1.1802x over previous
//
#include <hip/hip_runtime.h>
#include <hip/hip_bf16.h>

// LSTM: N=32, T=1024, D=H=512, bf16 dataset (verified round 3). Persistent
// cooperative kernel, 32 WGs; WG w owns gate-cols j in [16w,16w+16) of all 4
// gates, wave g = gate g. Weight column slices live bf16-transposed in LDS for
// the whole run. Per step: x-part MFMA first (h-independent, hides under
// barrier wait), then custom agent-scope epoch barrier, then h-part MFMA,
// gate exchange via LDS, fp32 c in LDS. h_t -> out[:,t,:]; step t+1 reads h
// from out[:,t,:] (per-step history, no overwrite race, 1 barrier/step).
//
// R4 change vs R3 (passed, 25.4 ms): grid.sync() (~24 us/step, system-scope
// CG barrier) -> monotone-counter barrier in ws (fetch_add RELEASE / spin
// ACQUIRE at agent scope, s_sleep(1) poll). Everything else identical.

#define NWG 32
#define LDW 520              // 512 + 8 pad shorts (16B-aligned rows)
#define SMEM_BYTES (2*64*LDW*2 + 4*32*16*4 + 512*4)   // 143360 B

typedef __attribute__((ext_vector_type(8))) short s16x8;
typedef __attribute__((ext_vector_type(4))) float f32x4;
typedef __attribute__((ext_vector_type(4))) float f4v;

__device__ __forceinline__ float b2f(unsigned short u) {
  unsigned v = ((unsigned)u) << 16;
  return __builtin_bit_cast(float, v);
}
__device__ __forceinline__ unsigned short f2b(float f) {
  unsigned u = __builtin_bit_cast(unsigned, f);
  unsigned r = (u + 0x7fffu + ((u >> 16) & 1u)) >> 16;  // RNE
  return (unsigned short)r;
}
__device__ __forceinline__ float sigmoidf_(float x) {
  return 1.f / (1.f + __expf(-x));
}
__device__ __forceinline__ float tanhf_(float x) {
  float ax = fabsf(x);
  float e = __expf(-2.f * ax);          // in (0,1], no overflow
  float th = (1.f - e) / (1.f + e);
  return copysignf(th, x);
}

// fp32[8] -> bf16 hi + lo fragments (kept for dtype-proofing; fp32 fallback)
__device__ __forceinline__ void split8(const float* p, s16x8& hi, s16x8& lo) {
  float tmp[8];
  *(f4v*)&tmp[0] = *(const f4v*)&p[0];
  *(f4v*)&tmp[4] = *(const f4v*)&p[4];
#pragma unroll
  for (int j = 0; j < 8; j++) {
    unsigned short h = f2b(tmp[j]);
    hi[j] = (short)h;
    lo[j] = (short)f2b(tmp[j] - b2f(h));
  }
}
__device__ __forceinline__ s16x8 cvt8(const float* p) {
  float tmp[8];
  *(f4v*)&tmp[0] = *(const f4v*)&p[0];
  *(f4v*)&tmp[4] = *(const f4v*)&p[4];
  s16x8 r;
#pragma unroll
  for (int j = 0; j < 8; j++) r[j] = (short)f2b(tmp[j]);
  return r;
}

// Uniform dtype sniff (one-time): bf16 normals vs fp32-as-halfwords.
__device__ __forceinline__ bool sniff_is_bf16(const unsigned short* wx) {
  int cnt = 0;
  for (int i = 0; i < 512; i++) {
    unsigned e = (wx[i] >> 7) & 0xFF;
    cnt += (e >= 0x60 && e <= 0x9F) ? 1 : 0;
  }
  return cnt >= 440;
}

template <bool F32>
__device__ __forceinline__ void lstm_body(
    const void* xv, const void* h0v, const void* Wxv, const void* Whv,
    const void* biasv, void* outv, unsigned* __restrict__ bar,
    unsigned char* smem) {
  unsigned short* WhS = (unsigned short*)smem;                    // [64][LDW]
  unsigned short* WxS = (unsigned short*)(smem + 64 * LDW * 2);   // [64][LDW]
  float* gatebuf = (float*)(smem + 2 * 64 * LDW * 2);             // [4*32][16]
  float* cbuf = (float*)(smem + 2 * 64 * LDW * 2 + 4 * 32 * 16 * 4); // [512]

  const unsigned short* xb = (const unsigned short*)xv;
  const float* xf = (const float*)xv;
  const unsigned short* h0b = (const unsigned short*)h0v;
  const float* h0f = (const float*)h0v;

  const int tid = threadIdx.x;
  const int g = tid >> 6;          // wave = gate (i,f,o,g)
  const int lane = tid & 63;
  const int lm = lane & 15;
  const int q = lane >> 4;
  const int w = blockIdx.x;        // owns cols w*16 .. w*16+15 of each gate

  // One-time staging of weight column slices -> LDS [col][k], bf16.
  for (int i = 0; i < 8; i++) {
    int id = tid + i * 256;        // 0..2047
    int gate = id & 3;
    int k = id >> 2;               // 0..511
    size_t base = (size_t)k * 2048 + gate * 512 + w * 16;
    if (F32) {
      const float* px = (const float*)Wxv + base;
      const float* ph = (const float*)Whv + base;
#pragma unroll
      for (int seg = 0; seg < 4; seg++) {
        f4v vx = *(const f4v*)(px + seg * 4);
        f4v vh = *(const f4v*)(ph + seg * 4);
#pragma unroll
        for (int j = 0; j < 4; j++) {
          WxS[(gate * 16 + seg * 4 + j) * LDW + k] = f2b(vx[j]);
          WhS[(gate * 16 + seg * 4 + j) * LDW + k] = f2b(vh[j]);
        }
      }
    } else {
      const unsigned short* px = (const unsigned short*)Wxv + base;
      const unsigned short* ph = (const unsigned short*)Whv + base;
      s16x8 vx0 = *(const s16x8*)&px[0];
      s16x8 vx1 = *(const s16x8*)&px[8];
      s16x8 vh0 = *(const s16x8*)&ph[0];
      s16x8 vh1 = *(const s16x8*)&ph[8];
#pragma unroll
      for (int j = 0; j < 8; j++) {
        WxS[(gate * 16 + j) * LDW + k]     = (unsigned short)vx0[j];
        WxS[(gate * 16 + 8 + j) * LDW + k] = (unsigned short)vx1[j];
        WhS[(gate * 16 + j) * LDW + k]     = (unsigned short)vh0[j];
        WhS[(gate * 16 + 8 + j) * LDW + k] = (unsigned short)vh1[j];
      }
    }
  }
  cbuf[tid] = 0.f;
  cbuf[tid + 256] = 0.f;

  float bv[2][4];
  for (int pp = 0; pp < 2; pp++) {
    int p = tid + pp * 256;
    int j = p & 15;
    for (int qq = 0; qq < 4; qq++) {
      int idx = qq * 512 + w * 16 + j;
      bv[pp][qq] = F32 ? ((const float*)biasv)[idx]
                       : b2f(((const unsigned short*)biasv)[idx]);
    }
  }
  __syncthreads();

  for (int t = 0; t < 1024; t++) {
    f32x4 acc0 = {0.f, 0.f, 0.f, 0.f};   // batch rows 0..15
    f32x4 acc1 = {0.f, 0.f, 0.f, 0.f};   // batch rows 16..31

    // ---- x-part (h-independent): issue BEFORE the barrier wait ----
    if (F32) {
      for (int kc = 0; kc < 16; kc++) {
        int k = kc * 32 + q * 8;
        s16x8 bfrag = *(const s16x8*)&WxS[(g * 16 + lm) * LDW + k];
        s16x8 a0 = cvt8(&xf[(size_t)(lm * 1024 + t) * 512 + k]);
        s16x8 a1 = cvt8(&xf[(size_t)((16 + lm) * 1024 + t) * 512 + k]);
        acc0 = __builtin_amdgcn_mfma_f32_16x16x32_bf16(a0, bfrag, acc0, 0, 0, 0);
        acc1 = __builtin_amdgcn_mfma_f32_16x16x32_bf16(a1, bfrag, acc1, 0, 0, 0);
      }
    } else {
      for (int kc = 0; kc < 16; kc++) {
        int k = kc * 32 + q * 8;
        s16x8 bfrag = *(const s16x8*)&WxS[(g * 16 + lm) * LDW + k];
        s16x8 a0 = *(const s16x8*)&xb[(size_t)(lm * 1024 + t) * 512 + k];
        s16x8 a1 = *(const s16x8*)&xb[(size_t)((16 + lm) * 1024 + t) * 512 + k];
        acc0 = __builtin_amdgcn_mfma_f32_16x16x32_bf16(a0, bfrag, acc0, 0, 0, 0);
        acc1 = __builtin_amdgcn_mfma_f32_16x16x32_bf16(a1, bfrag, acc1, 0, 0, 0);
      }
    }

    // ---- wait for h_{t-1} publication (monotone epoch barrier) ----
    if (t > 0) {
      if (tid == 0) {
        const unsigned target = (unsigned)t * NWG;
        int guard = 0;
        while (__hip_atomic_load(bar, __ATOMIC_ACQUIRE,
                                 __HIP_MEMORY_SCOPE_AGENT) < target) {
          __builtin_amdgcn_s_sleep(1);
          if (++guard > (1 << 25)) break;   // anti-hang; never taken when co-resident
        }
      }
      __syncthreads();   // all threads proceed only after h_{t-1} visible
    }

    // ---- h-part ----
    if (F32) {
      float* outf = (float*)outv;
      const float* hpf = (t == 0) ? h0f : outf + (size_t)(t - 1) * 512;
      const size_t hstride = (t == 0) ? 512 : (size_t)1024 * 512;
      for (int kc = 0; kc < 16; kc++) {
        int k = kc * 32 + q * 8;
        s16x8 bfrag = *(const s16x8*)&WhS[(g * 16 + lm) * LDW + k];
        s16x8 hi0, lo0, hi1, lo1;
        split8(&hpf[lm * hstride + k], hi0, lo0);
        split8(&hpf[(16 + lm) * hstride + k], hi1, lo1);
        acc0 = __builtin_amdgcn_mfma_f32_16x16x32_bf16(hi0, bfrag, acc0, 0, 0, 0);
        acc0 = __builtin_amdgcn_mfma_f32_16x16x32_bf16(lo0, bfrag, acc0, 0, 0, 0);
        acc1 = __builtin_amdgcn_mfma_f32_16x16x32_bf16(hi1, bfrag, acc1, 0, 0, 0);
        acc1 = __builtin_amdgcn_mfma_f32_16x16x32_bf16(lo1, bfrag, acc1, 0, 0, 0);
      }
    } else {
      unsigned short* outb = (unsigned short*)outv;
      const unsigned short* hpb = (t == 0) ? h0b : outb + (size_t)(t - 1) * 512;
      const size_t hstride = (t == 0) ? 512 : (size_t)1024 * 512;
      for (int kc = 0; kc < 16; kc++) {
        int k = kc * 32 + q * 8;
        s16x8 bfrag = *(const s16x8*)&WhS[(g * 16 + lm) * LDW + k];
        s16x8 a0 = *(const s16x8*)&hpb[lm * hstride + k];
        s16x8 a1 = *(const s16x8*)&hpb[(16 + lm) * hstride + k];
        acc0 = __builtin_amdgcn_mfma_f32_16x16x32_bf16(a0, bfrag, acc0, 0, 0, 0);
        acc1 = __builtin_amdgcn_mfma_f32_16x16x32_bf16(a1, bfrag, acc1, 0, 0, 0);
      }
    }

    // C/D layout: col = lane&15 (j), row = q*4 + reg (batch row in 16-block)
    for (int r = 0; r < 4; r++) {
      gatebuf[(g * 32 + q * 4 + r) * 16 + lm] = acc0[r];
      gatebuf[(g * 32 + 16 + q * 4 + r) * 16 + lm] = acc1[r];
    }
    __syncthreads();

    for (int pp = 0; pp < 2; pp++) {
      int p = tid + pp * 256;
      int n = p >> 4, j = p & 15;
      float ai = gatebuf[(0 * 32 + n) * 16 + j] + bv[pp][0];
      float af = gatebuf[(1 * 32 + n) * 16 + j] + bv[pp][1];
      float ao = gatebuf[(2 * 32 + n) * 16 + j] + bv[pp][2];
      float ag = gatebuf[(3 * 32 + n) * 16 + j] + bv[pp][3];
      float iG = sigmoidf_(ai);
      float fG = sigmoidf_(af);
      float oG = sigmoidf_(ao);
      float gG = tanhf_(ag);
      float c = fG * cbuf[p] + iG * gG;
      cbuf[p] = c;
      float h = oG * tanhf_(c);
      size_t oidx = (size_t)(n * 1024 + t) * 512 + w * 16 + j;
      if (F32) ((float*)outv)[oidx] = h;
      else     ((unsigned short*)outv)[oidx] = f2b(h);
    }
    __syncthreads();   // all h_t stores of this WG done before the release add

    if (t < 1023 && tid == 0) {
      __hip_atomic_fetch_add(bar, 1u, __ATOMIC_RELEASE,
                             __HIP_MEMORY_SCOPE_AGENT);
    }
  }
}

__global__ __launch_bounds__(256) void lstm_kernel(
    const void* x, const void* h0, const void* Wx, const void* Wh,
    const void* bias, void* out, unsigned* bar) {
  extern __shared__ unsigned char smem[];
  if (sniff_is_bf16((const unsigned short*)Wx))
    lstm_body<false>(x, h0, Wx, Wh, bias, out, bar, smem);
  else
    lstm_body<true>(x, h0, Wx, Wh, bias, out, bar, smem);
}

extern "C" void kernel_launch(void* const* d_in, const int* in_sizes, int n_in,
                              void* d_out, int out_size, void* d_ws, size_t ws_size,
                              hipStream_t stream) {
  const void* x  = d_in[0];
  const void* h0 = d_in[1];
  const void* Wx = d_in[2];
  const void* Wh = d_in[3];
  const void* b  = d_in[4];
  void* out = d_out;
  unsigned* bar = (unsigned*)d_ws;   // ws poisoned 0xAA each call -> zero it

  hipMemsetAsync(bar, 0, 128, stream);

  hipFuncSetAttribute((const void*)lstm_kernel,
                      hipFuncAttributeMaxDynamicSharedMemorySize, SMEM_BYTES);

  void* args[] = {(void*)&x, (void*)&h0, (void*)&Wx, (void*)&Wh,
                  (void*)&b, (void*)&out, (void*)&bar};
  hipLaunchCooperativeKernel((const void*)lstm_kernel, dim3(NWG), dim3(256),
                             args, SMEM_BYTES, stream);
}